// Round 3
// baseline (160.671 us; speedup 1.0000x reference)
//
#include <hip/hip_runtime.h>
#include <hip/hip_bf16.h>

#define TEMP_INV 14.285714285714286f  // 1/0.07
#define FSCALE 16.0f                  // fp8 pre-scale per operand
#define T1S (TEMP_INV / 256.0f)       // acc = 256*sim -> (sim-1)/T = acc*T1S - TEMP_INV

typedef __attribute__((ext_vector_type(4))) float f32x4;
typedef __attribute__((ext_vector_type(4))) int i32x4;
typedef __attribute__((ext_vector_type(8))) int i32x8;

// ---- row L2-normalize -> fp8 e4m3 (x16) in QUAD-MAJOR layout ----
// Distributed glab fill (4 rows/block, 1 write/wave); block 0 only zeroes
// gacc/dcnt. No histogram here (reduce_loss recomputes it in parallel).
__global__ __launch_bounds__(256) void norm_k(const float* __restrict__ feat,
                                              uchar* __restrict__ fq,
                                              const int* __restrict__ labels,
                                              const int* __restrict__ kptr,
                                              int* __restrict__ glab,
                                              float* __restrict__ gacc,
                                              int* __restrict__ dcnt,
                                              int N, int D) {
  const int row = (blockIdx.x * 256 + threadIdx.x) >> 6;
  const int lane = threadIdx.x & 63;
  if (row < N) {
    const float4* fr = (const float4*)(feat + (size_t)row * D);
    float4 v0 = fr[lane * 2];
    float4 v1 = fr[lane * 2 + 1];
    float ss = v0.x * v0.x + v0.y * v0.y + v0.z * v0.z + v0.w * v0.w +
               v1.x * v1.x + v1.y * v1.y + v1.z * v1.z + v1.w * v1.w;
    #pragma unroll
    for (int off = 32; off; off >>= 1) ss += __shfl_xor(ss, off, 64);
    const float inv = FSCALE / fmaxf(sqrtf(ss), 1e-12f);
    int w0 = 0, w1 = 0;
    w0 = __builtin_amdgcn_cvt_pk_fp8_f32(v0.x * inv, v0.y * inv, w0, false);
    w0 = __builtin_amdgcn_cvt_pk_fp8_f32(v0.z * inv, v0.w * inv, w0, true);
    w1 = __builtin_amdgcn_cvt_pk_fp8_f32(v1.x * inv, v1.y * inv, w1, false);
    w1 = __builtin_amdgcn_cvt_pk_fp8_f32(v1.z * inv, v1.w * inv, w1, true);
    uint2 o; o.x = (uint)w0; o.y = (uint)w1;
    const int pofs = (lane >> 4) * 128 + (lane & 3) * 32 + ((lane >> 2) & 3) * 8;
    *(uint2*)(fq + (size_t)row * D + pofs) = o;
    if (lane == 0) {
      const int k = *kptr;
      glab[row] = labels[(size_t)(row / k) * k];
    }
  }
  if (blockIdx.x == 0 && threadIdx.x < 3) {
    if (threadIdx.x < 2) gacc[threadIdx.x] = 0.f;
    else *dcnt = 0;
  }
}

// ---- fused MX-fp8 GEMM + masked-softmax-stats, upper-triangle blocks ----
// r16: BARRIER-FREE direct-global operands. fq (4 MB) is L2/L3-resident, so
// LDS staging was pure overhead (each staged byte read back only 2x). The
// quad-major fq layout makes each MFMA fragment two contiguous 16B global
// loads: fq[row*D + quad*32 + kb] / +16 (the XOR staging + swizzled ds_read
// of r13 compose to the identity). K-loop = 16 global_load_dwordx4 + 16 MFMA
// per k-block, no barriers, no LDS operand traffic; waves fully independent.
__global__ __launch_bounds__(256, 2) void gemm_k(const uchar* __restrict__ fq,
                                                 const int* __restrict__ glab,
                                                 float* __restrict__ part,
                                                 int N, int D) {
  __shared__ float sf[1024];
  const int t = threadIdx.x;
  const int lane = t & 63;
  const int wid = t >> 6;
  const int wrow = wid >> 1, wcol = wid & 1;
  const int quad = lane >> 4, l15 = lane & 15;

  const int nb = N / 128;
  const int total = nb * (nb + 1) / 2;
  int gidx = blockIdx.x;
  if ((total & 7) == 0) {
    const int per = total >> 3;
    gidx = (blockIdx.x & 7) * per + (blockIdx.x >> 3);
  }
  int idx = gidx, bi = 0;
  while (idx >= nb - bi) { idx -= nb - bi; bi++; }
  const int bj = bi + idx;
  const int i0 = bi * 128, j0 = bj * 128;
  const bool diagblk = (bi == bj);

  f32x4 acc[4][4];
  #pragma unroll
  for (int mi = 0; mi < 4; mi++)
    #pragma unroll
    for (int ni = 0; ni < 4; ni++) {
      f32x4 z = {0.f, 0.f, 0.f, 0.f};
      acc[mi][ni] = z;
    }

  // one base pointer per fragment row; all kt / lo-hi offsets are immediates.
  const uchar* ap[4];
  const uchar* bp[4];
  #pragma unroll
  for (int mi = 0; mi < 4; mi++)
    ap[mi] = fq + (size_t)(i0 + wrow * 64 + mi * 16 + l15) * D + quad * 32;
  #pragma unroll
  for (int ni = 0; ni < 4; ni++)
    bp[ni] = fq + (size_t)(j0 + wcol * 64 + ni * 16 + l15) * D + quad * 32;

#define KSTEP(kb)                                                             \
  {                                                                           \
    i32x8 bv[4];                                                              \
    _Pragma("unroll")                                                         \
    for (int ni = 0; ni < 4; ni++) {                                          \
      i32x4 lo = *(const i32x4*)(bp[ni] + (kb));                              \
      i32x4 hi = *(const i32x4*)(bp[ni] + (kb) + 16);                         \
      bv[ni] = (i32x8){lo.x, lo.y, lo.z, lo.w, hi.x, hi.y, hi.z, hi.w};       \
    }                                                                         \
    _Pragma("unroll")                                                         \
    for (int mi = 0; mi < 4; mi++) {                                          \
      i32x4 lo = *(const i32x4*)(ap[mi] + (kb));                              \
      i32x4 hi = *(const i32x4*)(ap[mi] + (kb) + 16);                         \
      i32x8 av = (i32x8){lo.x, lo.y, lo.z, lo.w, hi.x, hi.y, hi.z, hi.w};     \
      _Pragma("unroll")                                                       \
      for (int ni = 0; ni < 4; ni++)                                          \
        acc[mi][ni] = __builtin_amdgcn_mfma_scale_f32_16x16x128_f8f6f4(       \
            av, bv[ni], acc[mi][ni], 0, 0, 0, 127, 0, 127);                   \
    }                                                                         \
  }

  if (D == 512) {
    KSTEP(0) KSTEP(128) KSTEP(256) KSTEP(384)
  } else {
    for (int kb = 0; kb < D; kb += 128) KSTEP(kb)
  }
#undef KSTEP

  const int colbase = j0 + wcol * 64 + l15;
  int clab[4];
  #pragma unroll
  for (int ni = 0; ni < 4; ni++) clab[ni] = glab[colbase + ni * 16];

  float colE[4] = {0.f, 0.f, 0.f, 0.f};
  float colP[4] = {0.f, 0.f, 0.f, 0.f};

  #pragma unroll
  for (int mi = 0; mi < 4; mi++) {
    const int lrw = wrow * 64 + mi * 16 + quad * 4;
    #pragma unroll
    for (int r = 0; r < 4; r++) {
      const int row = i0 + lrw + r;
      const int rlab = glab[row];
      float Ssum = 0.f, Psum = 0.f;
      #pragma unroll
      for (int ni = 0; ni < 4; ni++) {
        const int col = colbase + ni * 16;
        const float val = acc[mi][ni][r];
        const float lg = fmaf(val, T1S, -TEMP_INV);
        const bool diag = diagblk && (row == col);
        const float e = diag ? 0.f : __expf(lg);
        const float pm = (!diag && rlab == clab[ni]) ? lg : 0.f;
        Ssum += e; Psum += pm;
        colE[ni] += e; colP[ni] += pm;
      }
      #pragma unroll
      for (int off = 8; off; off >>= 1) {
        Ssum += __shfl_xor(Ssum, off, 64);
        Psum += __shfl_xor(Psum, off, 64);
      }
      if (l15 == 0) {
        sf[wcol * 128 + lrw + r]       = Ssum;
        sf[256 + wcol * 128 + lrw + r] = Psum;
      }
    }
  }
  if (!diagblk) {
    #pragma unroll
    for (int ni = 0; ni < 4; ni++) {
      float e = colE[ni];
      float p = colP[ni];
      e += __shfl_xor(e, 16, 64);
      e += __shfl_xor(e, 32, 64);
      p += __shfl_xor(p, 16, 64);
      p += __shfl_xor(p, 32, 64);
      const int lcol = wcol * 64 + ni * 16 + l15;
      if (quad == 0) {
        sf[512 + wrow * 128 + lcol] = e;
        sf[768 + wrow * 128 + lcol] = p;
      }
    }
  }
  __syncthreads();
  float* dst = part + (size_t)gidx * 512;
  if (t < 128) {
    dst[t]       = sf[t] + sf[128 + t];
    dst[128 + t] = sf[256 + t] + sf[384 + t];
  } else if (!diagblk) {
    const int u = t - 128;
    dst[256 + u] = sf[512 + u] + sf[640 + u];
    dst[384 + u] = sf[768 + u] + sf[896 + u];
  }
}

// ---- gather partials (8-way sliced) + in-block histogram -> loss ----
__global__ __launch_bounds__(1024) void reduce_loss_k(const float* __restrict__ part,
                                                      const int* __restrict__ glab,
                                                      const int* __restrict__ labels,
                                                      const int* __restrict__ kptr,
                                                      float* __restrict__ gacc,
                                                      int* __restrict__ dcnt,
                                                      float* __restrict__ out, int N) {
  const int nb = N / 128;
  const int b = blockIdx.x;
  const int tt = threadIdx.x;
  const int t = tt & 127;    // row within strip
  const int sl = tt >> 7;    // slice 0..7
  const int k = *kptr;
  const int B = N / k;

  __shared__ int h[64];
  if (tt < 64) h[tt] = 0;
  __syncthreads();
  for (int g = tt; g < B; g += 1024) {
    int lb = labels[(size_t)g * k];
    if (lb >= 0 && lb < 64) atomicAdd(&h[lb], 1);
  }

  float S = 0.f, P = 0.f;
  const int base = b * nb - b * (b - 1) / 2;
  for (int bj = b + sl; bj < nb; bj += 8) {   // row-side partials
    const float* p = part + (size_t)(base + bj - b) * 512;
    S += p[t];
    P += p[128 + t];
  }
  for (int bi = sl; bi < b; bi += 8) {        // col-side partials (symmetry)
    const int idx = bi * nb - bi * (bi - 1) / 2 + (b - bi);
    const float* p = part + (size_t)idx * 512;
    S += p[256 + t];
    P += p[384 + t];
  }
  __shared__ float sS[8][128], sP[8][128];
  sS[sl][t] = S; sP[sl][t] = P;
  __syncthreads();
  float l = 0.f, v = 0.f;
  if (sl == 0) {
    S = 0.f; P = 0.f;
    #pragma unroll
    for (int s = 0; s < 8; s++) { S += sS[s][t]; P += sP[s][t]; }
    const int np = h[glab[b * 128 + t]] * k - 1;
    if (np > 0) {
      l = -(P - (float)np * logf(S + 1e-8f)) / (float)np;
      v = 1.f;
    }
  }
  #pragma unroll
  for (int off = 32; off; off >>= 1) {
    l += __shfl_xor(l, off, 64);
    v += __shfl_xor(v, off, 64);
  }
  __shared__ float sl16[16], sv16[16];
  if ((tt & 63) == 0) { sl16[tt >> 6] = l; sv16[tt >> 6] = v; }
  __syncthreads();
  if (tt == 0) {
    float L = 0.f, V = 0.f;
    #pragma unroll
    for (int i = 0; i < 16; i++) { L += sl16[i]; V += sv16[i]; }
    atomicAdd(&gacc[0], L);
    atomicAdd(&gacc[1], V);
    __threadfence();
    const int prev = atomicAdd(dcnt, 1);
    if (prev == (int)gridDim.x - 1) {
      const float Lf = atomicAdd(&gacc[0], 0.f);
      const float Vf = atomicAdd(&gacc[1], 0.f);
      out[0] = Lf / fmaxf(Vf, 1.f);
    }
  }
}

extern "C" void kernel_launch(void* const* d_in, const int* in_sizes, int n_in,
                              void* d_out, int out_size, void* d_ws, size_t ws_size,
                              hipStream_t stream) {
  const float* feat = (const float*)d_in[0];
  const int* labels = (const int*)d_in[1];
  const int* kptr   = (const int*)d_in[2];
  const int N = in_sizes[1];
  const int D = in_sizes[0] / N;  // 512

  const int nb = N / 128;
  const int total = nb * (nb + 1) / 2;

  char* ws = (char*)d_ws;
  uchar* fq = (uchar*)ws;
  size_t off = (size_t)N * D;  // fp8: 1 byte/elem
  float* part = (float*)(ws + off); off += (size_t)total * 512 * sizeof(float);
  int* glab   = (int*)(ws + off);   off += (size_t)N * sizeof(int);
  float* gacc = (float*)(ws + off); off += 2 * sizeof(float);
  int* dcnt   = (int*)(ws + off);   off += sizeof(int);

  norm_k<<<(N + 3) / 4, 256, 0, stream>>>(feat, fq, labels, kptr, glab,
                                          gacc, dcnt, N, D);
  gemm_k<<<total, 256, 0, stream>>>(fq, glab, part, N, D);
  reduce_loss_k<<<nb, 1024, 0, stream>>>(part, glab, labels, kptr, gacc, dcnt,
                                         (float*)d_out, N);
}

// Round 4
// 130.958 us; speedup vs baseline: 1.2269x; 1.2269x over previous
//
#include <hip/hip_runtime.h>
#include <hip/hip_bf16.h>

#define TEMP_INV 14.285714285714286f  // 1/0.07
#define FSCALE 16.0f                  // fp8 pre-scale per operand
#define T1S (TEMP_INV / 256.0f)       // acc = 256*sim -> (sim-1)/T = acc*T1S - TEMP_INV

typedef __attribute__((ext_vector_type(4))) float f32x4;
typedef __attribute__((ext_vector_type(4))) int i32x4;
typedef __attribute__((ext_vector_type(8))) int i32x8;

// ---- fq FRAGMENT-MAJOR layout ----
// fq is organized in 2KB tiles: tile(rg, kb) with rg = row/16, kb = kbyte/128.
// Within a tile, byte (row r16, k-offset o in [0,128)) lives at:
//   slot = ((o>>4)&1)*64 + (o>>5)*16 + r16 ;  addr = slot*16 + (o&15)
// Chosen so an MFMA fragment (lane = quad*16+l15 wants row l15,
// k = quad*32..+32) reads: lo16B at tile+lane*16, hi16B at tile+1024+lane*16
// -> two perfectly lane-consecutive 1KB global loads per fragment.

// ---- row L2-normalize -> fp8 e4m3 (x16) into fragment-major layout ----
__global__ __launch_bounds__(256) void norm_k(const float* __restrict__ feat,
                                              uchar* __restrict__ fq,
                                              const int* __restrict__ labels,
                                              const int* __restrict__ kptr,
                                              int* __restrict__ glab,
                                              float* __restrict__ gacc,
                                              int* __restrict__ dcnt,
                                              int N, int D) {
  const int row = (blockIdx.x * 256 + threadIdx.x) >> 6;
  const int lane = threadIdx.x & 63;
  if (row < N) {
    const float4* fr = (const float4*)(feat + (size_t)row * D);
    float4 v0 = fr[lane * 2];
    float4 v1 = fr[lane * 2 + 1];
    float ss = v0.x * v0.x + v0.y * v0.y + v0.z * v0.z + v0.w * v0.w +
               v1.x * v1.x + v1.y * v1.y + v1.z * v1.z + v1.w * v1.w;
    #pragma unroll
    for (int off = 32; off; off >>= 1) ss += __shfl_xor(ss, off, 64);
    const float inv = FSCALE / fmaxf(sqrtf(ss), 1e-12f);
    int w0 = 0, w1 = 0;
    w0 = __builtin_amdgcn_cvt_pk_fp8_f32(v0.x * inv, v0.y * inv, w0, false);
    w0 = __builtin_amdgcn_cvt_pk_fp8_f32(v0.z * inv, v0.w * inv, w0, true);
    w1 = __builtin_amdgcn_cvt_pk_fp8_f32(v1.x * inv, v1.y * inv, w1, false);
    w1 = __builtin_amdgcn_cvt_pk_fp8_f32(v1.z * inv, v1.w * inv, w1, true);
    uint2 o; o.x = (uint)w0; o.y = (uint)w1;
    // lane covers kbytes [lane*8, lane*8+8) of this row
    const int tkb  = lane >> 4;          // k-block tile
    const int quad = (lane >> 2) & 3;    // (kbyte%128)>>5
    const int half = (lane >> 1) & 1;    // (kbyte%32)>>4
    const int slot = half * 64 + quad * 16 + (row & 15);
    uchar* dstp = fq + (((size_t)(row >> 4) * (D >> 7) + tkb) << 11) +
                  slot * 16 + (lane & 1) * 8;
    *(uint2*)dstp = o;
    if (lane == 0) {
      const int k = *kptr;
      glab[row] = labels[(size_t)(row / k) * k];
    }
  }
  if (blockIdx.x == 0 && threadIdx.x < 3) {
    if (threadIdx.x < 2) gacc[threadIdx.x] = 0.f;
    else *dcnt = 0;
  }
}

// ---- fused MX-fp8 GEMM + masked-softmax-stats, upper-triangle blocks ----
// r17: barrier-free direct-global operands from FRAGMENT-MAJOR fq.
// Per k-step per wave: 16 lane-consecutive global_load_dwordx4 (1KB each,
// L2-served) + 16 mfma_scale. No LDS operand traffic, no barriers, waves
// fully independent; fully-unrolled K lets the compiler overlap next
// k-step's loads under current MFMAs. 128x128 tile, 4 waves (2x2 grid of
// 64x64 wave tiles), 4x4 frags/wave — epilogue identical to proven r13.
__global__ __launch_bounds__(256, 3) void gemm_k(const uchar* __restrict__ fq,
                                                 const int* __restrict__ glab,
                                                 float* __restrict__ part,
                                                 int N, int D) {
  __shared__ float sf[1024];
  const int t = threadIdx.x;
  const int lane = t & 63;
  const int wid = t >> 6;
  const int wrow = wid >> 1, wcol = wid & 1;
  const int quad = lane >> 4, l15 = lane & 15;

  const int nb = N / 128;
  const int total = nb * (nb + 1) / 2;
  int gidx = blockIdx.x;
  if ((total & 7) == 0) {
    const int per = total >> 3;
    gidx = (blockIdx.x & 7) * per + (blockIdx.x >> 3);
  }
  int idx = gidx, bi = 0;
  while (idx >= nb - bi) { idx -= nb - bi; bi++; }
  const int bj = bi + idx;
  const int i0 = bi * 128, j0 = bj * 128;
  const bool diagblk = (bi == bj);

  f32x4 acc[4][4];
  #pragma unroll
  for (int mi = 0; mi < 4; mi++)
    #pragma unroll
    for (int ni = 0; ni < 4; ni++) {
      f32x4 z = {0.f, 0.f, 0.f, 0.f};
      acc[mi][ni] = z;
    }

  const int ktiles = D >> 7;
  // panel bases: A row-group (i0/16 + wrow*4 + mi), B row-group (j0/16 + wcol*4 + ni)
  const uchar* ap = fq + (((size_t)((i0 >> 4) + wrow * 4) * ktiles) << 11) + lane * 16;
  const uchar* bp = fq + (((size_t)((j0 >> 4) + wcol * 4) * ktiles) << 11) + lane * 16;

#define KSTEP(kt)                                                             \
  {                                                                           \
    i32x8 bv[4];                                                              \
    _Pragma("unroll")                                                         \
    for (int ni = 0; ni < 4; ni++) {                                          \
      const uchar* p = bp + (((ni) * ktiles + (kt)) << 11);                   \
      i32x4 lo = *(const i32x4*)p;                                            \
      i32x4 hi = *(const i32x4*)(p + 1024);                                   \
      bv[ni] = (i32x8){lo.x, lo.y, lo.z, lo.w, hi.x, hi.y, hi.z, hi.w};       \
    }                                                                         \
    _Pragma("unroll")                                                         \
    for (int mi = 0; mi < 4; mi++) {                                          \
      const uchar* p = ap + (((mi) * ktiles + (kt)) << 11);                   \
      i32x4 lo = *(const i32x4*)p;                                            \
      i32x4 hi = *(const i32x4*)(p + 1024);                                   \
      i32x8 av = (i32x8){lo.x, lo.y, lo.z, lo.w, hi.x, hi.y, hi.z, hi.w};     \
      _Pragma("unroll")                                                       \
      for (int ni = 0; ni < 4; ni++)                                          \
        acc[mi][ni] = __builtin_amdgcn_mfma_scale_f32_16x16x128_f8f6f4(       \
            av, bv[ni], acc[mi][ni], 0, 0, 0, 127, 0, 127);                   \
    }                                                                         \
  }

  if (ktiles == 4) {
    KSTEP(0) KSTEP(1) KSTEP(2) KSTEP(3)
  } else {
    for (int kt = 0; kt < ktiles; kt++) KSTEP(kt)
  }
#undef KSTEP

  const int colbase = j0 + wcol * 64 + l15;
  int clab[4];
  #pragma unroll
  for (int ni = 0; ni < 4; ni++) clab[ni] = glab[colbase + ni * 16];

  float colE[4] = {0.f, 0.f, 0.f, 0.f};
  float colP[4] = {0.f, 0.f, 0.f, 0.f};

  #pragma unroll
  for (int mi = 0; mi < 4; mi++) {
    const int lrw = wrow * 64 + mi * 16 + quad * 4;
    #pragma unroll
    for (int r = 0; r < 4; r++) {
      const int row = i0 + lrw + r;
      const int rlab = glab[row];
      float Ssum = 0.f, Psum = 0.f;
      #pragma unroll
      for (int ni = 0; ni < 4; ni++) {
        const int col = colbase + ni * 16;
        const float val = acc[mi][ni][r];
        const float lg = fmaf(val, T1S, -TEMP_INV);
        const bool diag = diagblk && (row == col);
        const float e = diag ? 0.f : __expf(lg);
        const float pm = (!diag && rlab == clab[ni]) ? lg : 0.f;
        Ssum += e; Psum += pm;
        colE[ni] += e; colP[ni] += pm;
      }
      #pragma unroll
      for (int off = 8; off; off >>= 1) {
        Ssum += __shfl_xor(Ssum, off, 64);
        Psum += __shfl_xor(Psum, off, 64);
      }
      if (l15 == 0) {
        sf[wcol * 128 + lrw + r]       = Ssum;
        sf[256 + wcol * 128 + lrw + r] = Psum;
      }
    }
  }
  if (!diagblk) {
    #pragma unroll
    for (int ni = 0; ni < 4; ni++) {
      float e = colE[ni];
      float p = colP[ni];
      e += __shfl_xor(e, 16, 64);
      e += __shfl_xor(e, 32, 64);
      p += __shfl_xor(p, 16, 64);
      p += __shfl_xor(p, 32, 64);
      const int lcol = wcol * 64 + ni * 16 + l15;
      if (quad == 0) {
        sf[512 + wrow * 128 + lcol] = e;
        sf[768 + wrow * 128 + lcol] = p;
      }
    }
  }
  __syncthreads();
  float* dst = part + (size_t)gidx * 512;
  if (t < 128) {
    dst[t]       = sf[t] + sf[128 + t];
    dst[128 + t] = sf[256 + t] + sf[384 + t];
  } else if (!diagblk) {
    const int u = t - 128;
    dst[256 + u] = sf[512 + u] + sf[640 + u];
    dst[384 + u] = sf[768 + u] + sf[896 + u];
  }
}

// ---- gather partials (8-way sliced) + in-block histogram -> loss ----
__global__ __launch_bounds__(1024) void reduce_loss_k(const float* __restrict__ part,
                                                      const int* __restrict__ glab,
                                                      const int* __restrict__ labels,
                                                      const int* __restrict__ kptr,
                                                      float* __restrict__ gacc,
                                                      int* __restrict__ dcnt,
                                                      float* __restrict__ out, int N) {
  const int nb = N / 128;
  const int b = blockIdx.x;
  const int tt = threadIdx.x;
  const int t = tt & 127;    // row within strip
  const int sl = tt >> 7;    // slice 0..7
  const int k = *kptr;
  const int B = N / k;

  __shared__ int h[64];
  if (tt < 64) h[tt] = 0;
  __syncthreads();
  for (int g = tt; g < B; g += 1024) {
    int lb = labels[(size_t)g * k];
    if (lb >= 0 && lb < 64) atomicAdd(&h[lb], 1);
  }

  float S = 0.f, P = 0.f;
  const int base = b * nb - b * (b - 1) / 2;
  for (int bj = b + sl; bj < nb; bj += 8) {   // row-side partials
    const float* p = part + (size_t)(base + bj - b) * 512;
    S += p[t];
    P += p[128 + t];
  }
  for (int bi = sl; bi < b; bi += 8) {        // col-side partials (symmetry)
    const int idx = bi * nb - bi * (bi - 1) / 2 + (b - bi);
    const float* p = part + (size_t)idx * 512;
    S += p[256 + t];
    P += p[384 + t];
  }
  __shared__ float sS[8][128], sP[8][128];
  sS[sl][t] = S; sP[sl][t] = P;
  __syncthreads();
  float l = 0.f, v = 0.f;
  if (sl == 0) {
    S = 0.f; P = 0.f;
    #pragma unroll
    for (int s = 0; s < 8; s++) { S += sS[s][t]; P += sP[s][t]; }
    const int np = h[glab[b * 128 + t]] * k - 1;
    if (np > 0) {
      l = -(P - (float)np * logf(S + 1e-8f)) / (float)np;
      v = 1.f;
    }
  }
  #pragma unroll
  for (int off = 32; off; off >>= 1) {
    l += __shfl_xor(l, off, 64);
    v += __shfl_xor(v, off, 64);
  }
  __shared__ float sl16[16], sv16[16];
  if ((tt & 63) == 0) { sl16[tt >> 6] = l; sv16[tt >> 6] = v; }
  __syncthreads();
  if (tt == 0) {
    float L = 0.f, V = 0.f;
    #pragma unroll
    for (int i = 0; i < 16; i++) { L += sl16[i]; V += sv16[i]; }
    atomicAdd(&gacc[0], L);
    atomicAdd(&gacc[1], V);
    __threadfence();
    const int prev = atomicAdd(dcnt, 1);
    if (prev == (int)gridDim.x - 1) {
      const float Lf = atomicAdd(&gacc[0], 0.f);
      const float Vf = atomicAdd(&gacc[1], 0.f);
      out[0] = Lf / fmaxf(Vf, 1.f);
    }
  }
}

extern "C" void kernel_launch(void* const* d_in, const int* in_sizes, int n_in,
                              void* d_out, int out_size, void* d_ws, size_t ws_size,
                              hipStream_t stream) {
  const float* feat = (const float*)d_in[0];
  const int* labels = (const int*)d_in[1];
  const int* kptr   = (const int*)d_in[2];
  const int N = in_sizes[1];
  const int D = in_sizes[0] / N;  // 512

  const int nb = N / 128;
  const int total = nb * (nb + 1) / 2;

  char* ws = (char*)d_ws;
  uchar* fq = (uchar*)ws;
  size_t off = (size_t)N * D;  // fp8: 1 byte/elem
  float* part = (float*)(ws + off); off += (size_t)total * 512 * sizeof(float);
  int* glab   = (int*)(ws + off);   off += (size_t)N * sizeof(int);
  float* gacc = (float*)(ws + off); off += 2 * sizeof(float);
  int* dcnt   = (int*)(ws + off);   off += sizeof(int);

  norm_k<<<(N + 3) / 4, 256, 0, stream>>>(feat, fq, labels, kptr, glab,
                                          gacc, dcnt, N, D);
  gemm_k<<<total, 256, 0, stream>>>(fq, glab, part, N, D);
  reduce_loss_k<<<nb, 1024, 0, stream>>>(part, glab, labels, kptr, gacc, dcnt,
                                         (float*)d_out, N);
}

// Round 5
// 129.831 us; speedup vs baseline: 1.2375x; 1.0087x over previous
//
#include <hip/hip_runtime.h>
#include <hip/hip_bf16.h>

#define TEMP_INV 14.285714285714286f  // 1/0.07
#define FSCALE 16.0f                  // fp8 pre-scale per operand
#define T1S (TEMP_INV / 256.0f)       // acc = 256*sim -> (sim-1)/T = acc*T1S - TEMP_INV

typedef __attribute__((ext_vector_type(4))) float f32x4;
typedef __attribute__((ext_vector_type(4))) int i32x4;
typedef __attribute__((ext_vector_type(8))) int i32x8;

// ---- fq FRAGMENT-MAJOR layout ----
// fq is organized in 2KB tiles: tile(rg, kb) with rg = row/16, kb = kbyte/128.
// Within a tile, byte (row r16, k-offset o in [0,128)) lives at:
//   slot = ((o>>4)&1)*64 + (o>>5)*16 + r16 ;  addr = slot*16 + (o&15)
// Chosen so an MFMA fragment (lane = quad*16+l15 wants row l15,
// k = quad*32..+32) reads: lo16B at tile+lane*16, hi16B at tile+1024+lane*16
// -> two perfectly lane-consecutive 1KB global loads per fragment.

// ---- row L2-normalize -> fp8 e4m3 (x16) into fragment-major layout ----
__global__ __launch_bounds__(256) void norm_k(const float* __restrict__ feat,
                                              uchar* __restrict__ fq,
                                              const int* __restrict__ labels,
                                              const int* __restrict__ kptr,
                                              int* __restrict__ glab,
                                              float* __restrict__ gacc,
                                              int* __restrict__ dcnt,
                                              int N, int D) {
  const int row = (blockIdx.x * 256 + threadIdx.x) >> 6;
  const int lane = threadIdx.x & 63;
  if (row < N) {
    const float4* fr = (const float4*)(feat + (size_t)row * D);
    float4 v0 = fr[lane * 2];
    float4 v1 = fr[lane * 2 + 1];
    float ss = v0.x * v0.x + v0.y * v0.y + v0.z * v0.z + v0.w * v0.w +
               v1.x * v1.x + v1.y * v1.y + v1.z * v1.z + v1.w * v1.w;
    #pragma unroll
    for (int off = 32; off; off >>= 1) ss += __shfl_xor(ss, off, 64);
    const float inv = FSCALE / fmaxf(sqrtf(ss), 1e-12f);
    int w0 = 0, w1 = 0;
    w0 = __builtin_amdgcn_cvt_pk_fp8_f32(v0.x * inv, v0.y * inv, w0, false);
    w0 = __builtin_amdgcn_cvt_pk_fp8_f32(v0.z * inv, v0.w * inv, w0, true);
    w1 = __builtin_amdgcn_cvt_pk_fp8_f32(v1.x * inv, v1.y * inv, w1, false);
    w1 = __builtin_amdgcn_cvt_pk_fp8_f32(v1.z * inv, v1.w * inv, w1, true);
    uint2 o; o.x = (uint)w0; o.y = (uint)w1;
    // lane covers kbytes [lane*8, lane*8+8) of this row
    const int tkb  = lane >> 4;          // k-block tile
    const int quad = (lane >> 2) & 3;    // (kbyte%128)>>5
    const int half = (lane >> 1) & 1;    // (kbyte%32)>>4
    const int slot = half * 64 + quad * 16 + (row & 15);
    uchar* dstp = fq + (((size_t)(row >> 4) * (D >> 7) + tkb) << 11) +
                  slot * 16 + (lane & 1) * 8;
    *(uint2*)dstp = o;
    if (lane == 0) {
      const int k = *kptr;
      glab[row] = labels[(size_t)(row / k) * k];
    }
  }
  if (blockIdx.x == 0 && threadIdx.x < 3) {
    if (threadIdx.x < 2) gacc[threadIdx.x] = 0.f;
    else *dcnt = 0;
  }
}

// ---- fused MX-fp8 GEMM + masked-softmax-stats, upper-triangle blocks ----
// r18: r17's barrier-free fragment-major direct-global structure + explicit
// modulo-2 REGISTER PREFETCH. Two named fragment buffers X/Y (static names,
// no runtime indexing): LOAD(0->X) LOAD(1->Y) MFMA(X) LOAD(2->X) MFMA(Y)
// LOAD(3->Y) MFMA(X) MFMA(Y). Each MFMA cluster's vmcnt covers loads issued
// two steps earlier -> L2 latency hidden under 16 MFMAs + 16 load-issues.
// ~210 VGPR (acc 64 + 2x64 operands), 2 waves/SIMD.
__global__ __launch_bounds__(256, 2) void gemm_k(const uchar* __restrict__ fq,
                                                 const int* __restrict__ glab,
                                                 float* __restrict__ part,
                                                 int N, int D) {
  __shared__ float sf[1024];
  const int t = threadIdx.x;
  const int lane = t & 63;
  const int wid = t >> 6;
  const int wrow = wid >> 1, wcol = wid & 1;
  const int quad = lane >> 4, l15 = lane & 15;

  const int nb = N / 128;
  const int total = nb * (nb + 1) / 2;
  int gidx = blockIdx.x;
  if ((total & 7) == 0) {
    const int per = total >> 3;
    gidx = (blockIdx.x & 7) * per + (blockIdx.x >> 3);
  }
  int idx = gidx, bi = 0;
  while (idx >= nb - bi) { idx -= nb - bi; bi++; }
  const int bj = bi + idx;
  const int i0 = bi * 128, j0 = bj * 128;
  const bool diagblk = (bi == bj);

  f32x4 acc[4][4];
  #pragma unroll
  for (int mi = 0; mi < 4; mi++)
    #pragma unroll
    for (int ni = 0; ni < 4; ni++) {
      f32x4 z = {0.f, 0.f, 0.f, 0.f};
      acc[mi][ni] = z;
    }

  const int ktiles = D >> 7;
  // panel bases: A row-group (i0/16 + wrow*4 + mi), B row-group (j0/16 + wcol*4 + ni)
  const uchar* ap = fq + (((size_t)((i0 >> 4) + wrow * 4) * ktiles) << 11) + lane * 16;
  const uchar* bp = fq + (((size_t)((j0 >> 4) + wcol * 4) * ktiles) << 11) + lane * 16;

#define LOADF(dst, base, idx, kt)                                             \
  {                                                                           \
    const uchar* p_ = (base) + ((((idx) * ktiles) + (kt)) << 11);             \
    i32x4 lo_ = *(const i32x4*)p_;                                            \
    i32x4 hi_ = *(const i32x4*)(p_ + 1024);                                   \
    dst = (i32x8){lo_.x, lo_.y, lo_.z, lo_.w, hi_.x, hi_.y, hi_.z, hi_.w};    \
  }

#define KLOAD(kt, A0, A1, A2, A3, B0, B1, B2, B3)                             \
  LOADF(B0, bp, 0, kt) LOADF(B1, bp, 1, kt)                                   \
  LOADF(B2, bp, 2, kt) LOADF(B3, bp, 3, kt)                                   \
  LOADF(A0, ap, 0, kt) LOADF(A1, ap, 1, kt)                                   \
  LOADF(A2, ap, 2, kt) LOADF(A3, ap, 3, kt)

#define MF(mi, ni, A, B)                                                      \
  acc[mi][ni] = __builtin_amdgcn_mfma_scale_f32_16x16x128_f8f6f4(             \
      A, B, acc[mi][ni], 0, 0, 0, 127, 0, 127);

#define KMFMA(A0, A1, A2, A3, B0, B1, B2, B3)                                 \
  MF(0, 0, A0, B0) MF(0, 1, A0, B1) MF(0, 2, A0, B2) MF(0, 3, A0, B3)        \
  MF(1, 0, A1, B0) MF(1, 1, A1, B1) MF(1, 2, A1, B2) MF(1, 3, A1, B3)        \
  MF(2, 0, A2, B0) MF(2, 1, A2, B1) MF(2, 2, A2, B2) MF(2, 3, A2, B3)        \
  MF(3, 0, A3, B0) MF(3, 1, A3, B1) MF(3, 2, A3, B2) MF(3, 3, A3, B3)

  if (ktiles == 4) {
    i32x8 xa0, xa1, xa2, xa3, xb0, xb1, xb2, xb3;
    i32x8 ya0, ya1, ya2, ya3, yb0, yb1, yb2, yb3;
    KLOAD(0, xa0, xa1, xa2, xa3, xb0, xb1, xb2, xb3)
    KLOAD(1, ya0, ya1, ya2, ya3, yb0, yb1, yb2, yb3)
    KMFMA(xa0, xa1, xa2, xa3, xb0, xb1, xb2, xb3)      // kt0 (kt1 in flight)
    KLOAD(2, xa0, xa1, xa2, xa3, xb0, xb1, xb2, xb3)
    KMFMA(ya0, ya1, ya2, ya3, yb0, yb1, yb2, yb3)      // kt1 (kt2 in flight)
    KLOAD(3, ya0, ya1, ya2, ya3, yb0, yb1, yb2, yb3)
    KMFMA(xa0, xa1, xa2, xa3, xb0, xb1, xb2, xb3)      // kt2 (kt3 in flight)
    KMFMA(ya0, ya1, ya2, ya3, yb0, yb1, yb2, yb3)      // kt3
  } else {
    for (int kt = 0; kt < ktiles; kt++) {
      i32x8 xa0, xa1, xa2, xa3, xb0, xb1, xb2, xb3;
      KLOAD(kt, xa0, xa1, xa2, xa3, xb0, xb1, xb2, xb3)
      KMFMA(xa0, xa1, xa2, xa3, xb0, xb1, xb2, xb3)
    }
  }
#undef LOADF
#undef KLOAD
#undef MF
#undef KMFMA

  const int colbase = j0 + wcol * 64 + l15;
  int clab[4];
  #pragma unroll
  for (int ni = 0; ni < 4; ni++) clab[ni] = glab[colbase + ni * 16];

  float colE[4] = {0.f, 0.f, 0.f, 0.f};
  float colP[4] = {0.f, 0.f, 0.f, 0.f};

  #pragma unroll
  for (int mi = 0; mi < 4; mi++) {
    const int lrw = wrow * 64 + mi * 16 + quad * 4;
    #pragma unroll
    for (int r = 0; r < 4; r++) {
      const int row = i0 + lrw + r;
      const int rlab = glab[row];
      float Ssum = 0.f, Psum = 0.f;
      #pragma unroll
      for (int ni = 0; ni < 4; ni++) {
        const int col = colbase + ni * 16;
        const float val = acc[mi][ni][r];
        const float lg = fmaf(val, T1S, -TEMP_INV);
        const bool diag = diagblk && (row == col);
        const float e = diag ? 0.f : __expf(lg);
        const float pm = (!diag && rlab == clab[ni]) ? lg : 0.f;
        Ssum += e; Psum += pm;
        colE[ni] += e; colP[ni] += pm;
      }
      #pragma unroll
      for (int off = 8; off; off >>= 1) {
        Ssum += __shfl_xor(Ssum, off, 64);
        Psum += __shfl_xor(Psum, off, 64);
      }
      if (l15 == 0) {
        sf[wcol * 128 + lrw + r]       = Ssum;
        sf[256 + wcol * 128 + lrw + r] = Psum;
      }
    }
  }
  if (!diagblk) {
    #pragma unroll
    for (int ni = 0; ni < 4; ni++) {
      float e = colE[ni];
      float p = colP[ni];
      e += __shfl_xor(e, 16, 64);
      e += __shfl_xor(e, 32, 64);
      p += __shfl_xor(p, 16, 64);
      p += __shfl_xor(p, 32, 64);
      const int lcol = wcol * 64 + ni * 16 + l15;
      if (quad == 0) {
        sf[512 + wrow * 128 + lcol] = e;
        sf[768 + wrow * 128 + lcol] = p;
      }
    }
  }
  __syncthreads();
  float* dst = part + (size_t)gidx * 512;
  if (t < 128) {
    dst[t]       = sf[t] + sf[128 + t];
    dst[128 + t] = sf[256 + t] + sf[384 + t];
  } else if (!diagblk) {
    const int u = t - 128;
    dst[256 + u] = sf[512 + u] + sf[640 + u];
    dst[384 + u] = sf[768 + u] + sf[896 + u];
  }
}

// ---- gather partials (8-way sliced) + in-block histogram -> loss ----
__global__ __launch_bounds__(1024) void reduce_loss_k(const float* __restrict__ part,
                                                      const int* __restrict__ glab,
                                                      const int* __restrict__ labels,
                                                      const int* __restrict__ kptr,
                                                      float* __restrict__ gacc,
                                                      int* __restrict__ dcnt,
                                                      float* __restrict__ out, int N) {
  const int nb = N / 128;
  const int b = blockIdx.x;
  const int tt = threadIdx.x;
  const int t = tt & 127;    // row within strip
  const int sl = tt >> 7;    // slice 0..7
  const int k = *kptr;
  const int B = N / k;

  __shared__ int h[64];
  if (tt < 64) h[tt] = 0;
  __syncthreads();
  for (int g = tt; g < B; g += 1024) {
    int lb = labels[(size_t)g * k];
    if (lb >= 0 && lb < 64) atomicAdd(&h[lb], 1);
  }

  float S = 0.f, P = 0.f;
  const int base = b * nb - b * (b - 1) / 2;
  for (int bj = b + sl; bj < nb; bj += 8) {   // row-side partials
    const float* p = part + (size_t)(base + bj - b) * 512;
    S += p[t];
    P += p[128 + t];
  }
  for (int bi = sl; bi < b; bi += 8) {        // col-side partials (symmetry)
    const int idx = bi * nb - bi * (bi - 1) / 2 + (b - bi);
    const float* p = part + (size_t)idx * 512;
    S += p[256 + t];
    P += p[384 + t];
  }
  __shared__ float sS[8][128], sP[8][128];
  sS[sl][t] = S; sP[sl][t] = P;
  __syncthreads();
  float l = 0.f, v = 0.f;
  if (sl == 0) {
    S = 0.f; P = 0.f;
    #pragma unroll
    for (int s = 0; s < 8; s++) { S += sS[s][t]; P += sP[s][t]; }
    const int np = h[glab[b * 128 + t]] * k - 1;
    if (np > 0) {
      l = -(P - (float)np * logf(S + 1e-8f)) / (float)np;
      v = 1.f;
    }
  }
  #pragma unroll
  for (int off = 32; off; off >>= 1) {
    l += __shfl_xor(l, off, 64);
    v += __shfl_xor(v, off, 64);
  }
  __shared__ float sl16[16], sv16[16];
  if ((tt & 63) == 0) { sl16[tt >> 6] = l; sv16[tt >> 6] = v; }
  __syncthreads();
  if (tt == 0) {
    float L = 0.f, V = 0.f;
    #pragma unroll
    for (int i = 0; i < 16; i++) { L += sl16[i]; V += sv16[i]; }
    atomicAdd(&gacc[0], L);
    atomicAdd(&gacc[1], V);
    __threadfence();
    const int prev = atomicAdd(dcnt, 1);
    if (prev == (int)gridDim.x - 1) {
      const float Lf = atomicAdd(&gacc[0], 0.f);
      const float Vf = atomicAdd(&gacc[1], 0.f);
      out[0] = Lf / fmaxf(Vf, 1.f);
    }
  }
}

extern "C" void kernel_launch(void* const* d_in, const int* in_sizes, int n_in,
                              void* d_out, int out_size, void* d_ws, size_t ws_size,
                              hipStream_t stream) {
  const float* feat = (const float*)d_in[0];
  const int* labels = (const int*)d_in[1];
  const int* kptr   = (const int*)d_in[2];
  const int N = in_sizes[1];
  const int D = in_sizes[0] / N;  // 512

  const int nb = N / 128;
  const int total = nb * (nb + 1) / 2;

  char* ws = (char*)d_ws;
  uchar* fq = (uchar*)ws;
  size_t off = (size_t)N * D;  // fp8: 1 byte/elem
  float* part = (float*)(ws + off); off += (size_t)total * 512 * sizeof(float);
  int* glab   = (int*)(ws + off);   off += (size_t)N * sizeof(int);
  float* gacc = (float*)(ws + off); off += 2 * sizeof(float);
  int* dcnt   = (int*)(ws + off);   off += sizeof(int);

  norm_k<<<(N + 3) / 4, 256, 0, stream>>>(feat, fq, labels, kptr, glab,
                                          gacc, dcnt, N, D);
  gemm_k<<<total, 256, 0, stream>>>(fq, glab, part, N, D);
  reduce_loss_k<<<nb, 1024, 0, stream>>>(part, glab, labels, kptr, gacc, dcnt,
                                         (float*)d_out, N);
}